// Round 17
// baseline (70.383 us; speedup 1.0000x reference)
//
#include <hip/hip_runtime.h>
#include <hip/hip_bf16.h>
#include <stdint.h>
#include <stddef.h>

// ---------------------------------------------------------------------------
// FixedEmbedderNN — round 17: r15 (known-good, 67.7us) + two safe deltas:
//  (a) bias staging as ONE full-wave GLDS (bf1p|boutp contiguous in ws,
//      bf1l|boll contiguous in LDS);
//  (b) s_setprio(1) around GEMM2'/GEMM3' MFMA clusters (tail has wave
//      role-diversity: waves 8-15 parked at barrier).
// Everything else verbatim from the verified r15 kernel.
// ---------------------------------------------------------------------------

typedef __attribute__((ext_vector_type(8))) short short8;
typedef __attribute__((ext_vector_type(4))) float f32x4;
typedef __attribute__((ext_vector_type(2))) float f32x2;
typedef __attribute__((ext_vector_type(2))) uint32_t uint32x2;

#define LN_EPS 1e-5f

#define GLDS16(g, l) __builtin_amdgcn_global_load_lds( \
    (const __attribute__((address_space(1))) uint32_t*)(g), \
    (__attribute__((address_space(3))) uint32_t*)(l), 16, 0, 0)

__device__ __forceinline__ float bflo(uint32_t u){ union{uint32_t u;float f;} c; c.u = u<<16; return c.f; }
__device__ __forceinline__ float bfhi(uint32_t u){ union{uint32_t u;float f;} c; c.u = u&0xffff0000u; return c.f; }
__device__ __forceinline__ uint16_t f2bf(float f){
  union{ __hip_bfloat16 h; uint16_t u; } c; c.h = __float2bfloat16(f); return c.u;
}
__device__ __forceinline__ uint32_t cvtpk(float lo, float hi){
  uint32_t r; asm("v_cvt_pk_bf16_f32 %0, %1, %2" : "=v"(r) : "v"(lo), "v"(hi)); return r;
}

// ---------------- precompute kernel 1 (no deps) — r11 verbatim ----------------
__global__ __launch_bounds__(128) void pre1(
    const float* __restrict__ W_num, const float* __restrict__ b_num,
    const float* __restrict__ W_in,  const float* __restrict__ b_in,
    const float* __restrict__ W1,    const float* __restrict__ b1,
    const float* __restrict__ W2,    const float* __restrict__ b2,
    const float* __restrict__ W_out, const float* __restrict__ b_out,
    const float* __restrict__ ln_g,  const float* __restrict__ ln_b,
    float* __restrict__ WLf,    // [2][128][128]
    float* __restrict__ Bnum,   // [21][128]
    float* __restrict__ bfold,  // [2][128]
    uint16_t* __restrict__ woutp, // Wout' transposed pack
    float* __restrict__ boutp)    // bout' permuted [g*32+t*4+r]
{
  const int b = blockIdx.x, j = threadIdx.x;
  if (b < 256) {                       // WL = W1@W2 per layer (4-way ILP)
    const int l = b >> 7, k = b & 127;
    const float* w1r = W1 + (l*128 + k)*256;
    const float* w2  = W2 + l*256*128;
    float sa = 0.f, sb = 0.f, sc = 0.f, sd = 0.f;
    for (int m = 0; m < 256; m += 4) {
      sa = fmaf(w1r[m],   w2[m*128 + j],       sa);
      sb = fmaf(w1r[m+1], w2[(m+1)*128 + j],   sb);
      sc = fmaf(w1r[m+2], w2[(m+2)*128 + j],   sc);
      sd = fmaf(w1r[m+3], w2[(m+3)*128 + j],   sd);
    }
    WLf[(l*128 + k)*128 + j] = (sa + sb) + (sc + sd);
  } else if (b < 277) {                // Bnum rows
    const int r = b - 256;
    if (r < 20) {
      const float* wn = W_num + r*32;
      const float* wi = W_in + (size_t)(20 + r)*32*128;
      float s = 0.f;
      for (int e = 0; e < 32; e++) s = fmaf(wn[e], wi[e*128 + j], s);
      Bnum[r*128 + j] = s;
    } else {
      float s = b_in[j];
      for (int f = 0; f < 20; f++) {
        const float* bn = b_num + f*32;
        const float* wi = W_in + (size_t)(20 + f)*32*128;
        for (int e = 0; e < 32; e++) s = fmaf(bn[e], wi[e*128 + j], s);
      }
      Bnum[20*128 + j] = s;
    }
  } else if (b < 279) {                // bfold = b1@W2 + b2
    const int l = b - 277;
    const float* b1r = b1 + l*256;
    const float* w2  = W2 + l*256*128;
    float s = b2[l*128 + j];
    for (int k = 0; k < 256; k++) s = fmaf(b1r[k], w2[k*128 + j], s);
    bfold[l*128 + j] = s;
  } else if (b < 311) {                // woutp: Wout' = diag(g1)@W_out, transposed A-pack
    const int p = b - 279, t = p >> 2, ks = p & 3;
    const int lane = j & 63, rep = j >> 6;
    const int col = 16*t + (lane & 15);
    for (int ii = 0; ii < 4; ii++) {
      const int i = rep*4 + ii;
      const int k = 32*ks + 8*(lane >> 4) + i;
      woutp[((t*4 + ks)*64 + lane)*8 + i] = f2bf(ln_g[128 + k] * W_out[k*128 + col]);
    }
  } else {                             // boutp (permuted): b1n@W_out + b_out
    const int t = (j >> 2) & 7, g = j >> 5, r = j & 3;
    const int col = 16*t + 4*g + r;
    float s = b_out[col];
    for (int k = 0; k < 128; k++) s = fmaf(ln_b[128 + k], W_out[k*128 + col], s);
    boutp[j] = s;
  }
}

// ---------------- precompute kernel 2 (depends on pre1) — r11 verbatim --------
__global__ __launch_bounds__(128) void pre2(
    const float* __restrict__ emb, const float* __restrict__ W_in,
    const float* __restrict__ ln_g, const float* __restrict__ ln_b,
    const float* __restrict__ WLf, const float* __restrict__ Bnum,
    const float* __restrict__ bfold,
    uint16_t* __restrict__ tcatp, // [2][20][50][64] bf16 slot-major
    uint16_t* __restrict__ wl2p,  // WL1' transposed pack
    float* __restrict__ bf1p,     // bf1' permuted
    uint16_t* __restrict__ a1p)   // A1^T pack, 8-run col map
{
  const int b = blockIdx.x, j = threadIdx.x;
  __shared__ float sh[128];
  if (b < 1000) {                      // Tcat1 = emb@W_in_slice@WL_0, slot-major store
    const int f = b / 50, c = b % 50;
    const float* e  = emb + (f*50 + c)*32;
    const float* wi = W_in + (size_t)f*32*128;
    float s = 0.f;
    for (int k = 0; k < 32; k++) s = fmaf(e[k], wi[k*128 + j], s);
    sh[j] = s;
    __syncthreads();
    float sa = 0.f, sb = 0.f, sc = 0.f, sd = 0.f;    // 4-way ILP
    for (int k = 0; k < 128; k += 4) {
      sa = fmaf(sh[k],   WLf[k*128 + j],       sa);
      sb = fmaf(sh[k+1], WLf[(k+1)*128 + j],   sb);
      sc = fmaf(sh[k+2], WLf[(k+2)*128 + j],   sc);
      sd = fmaf(sh[k+3], WLf[(k+3)*128 + j],   sd);
    }
    const float s2 = (sa + sb) + (sc + sd);
    const int t = j >> 4, g = (j >> 2) & 3, r = j & 3;
    const int h = t >> 2, jj = t & 3;
    const int slot = 2*g + (jj >> 1);
    tcatp[((h*20 + f)*50 + c)*64 + slot*8 + (jj & 1)*4 + r] = f2bf(s2);
  } else if (b < 1032) {               // wl2p: WL1' = diag(g0)@WL_1, transposed A-pack
    const int p = b - 1000, t = p >> 2, ks = p & 3;
    const int lane = j & 63, rep = j >> 6;
    const int col = 16*t + (lane & 15);
    const float* wl1 = WLf + 16384;
    for (int ii = 0; ii < 4; ii++) {
      const int i = rep*4 + ii;
      const int k = 32*ks + 8*(lane >> 4) + i;
      wl2p[((t*4 + ks)*64 + lane)*8 + i] = f2bf(ln_g[k] * wl1[k*128 + col]);
    }
  } else if (b == 1032) {              // bf1p (permuted): b0@WL_1 + bfold_1
    const int t = (j >> 2) & 7, g = j >> 5, r = j & 3;
    const int col = 16*t + 4*g + r;
    const float* wl1 = WLf + 16384;
    float s = bfold[128 + col];
    for (int k = 0; k < 128; k++) s = fmaf(ln_b[k], wl1[k*128 + col], s);
    bf1p[j] = s;
  } else {                             // a1p with 8-run col map (4-way ILP)
    const int t = b - 1033;
    const int lane = j & 63, rep = j >> 6;
    const int p = lane & 15;
    const int col = 32*(t >> 1) + 8*(p >> 2) + 4*(t & 1) + (p & 3);
    for (int ii = 0; ii < 4; ii++) {
      const int i = rep*4 + ii;
      const int k = 8*(lane >> 4) + i;
      float v = 0.f;
      if (k <= 20) {
        if (k == 20) v = bfold[col];
        float va = 0.f, vb = 0.f, vc = 0.f, vd = 0.f;
        for (int m = 0; m < 128; m += 4) {
          va = fmaf(Bnum[k*128 + m],   WLf[m*128 + col],       va);
          vb = fmaf(Bnum[k*128 + m+1], WLf[(m+1)*128 + col],   vb);
          vc = fmaf(Bnum[k*128 + m+2], WLf[(m+2)*128 + col],   vc);
          vd = fmaf(Bnum[k*128 + m+3], WLf[(m+3)*128 + col],   vd);
        }
        v += (va + vb) + (vc + vd);
      }
      a1p[(t*64 + lane)*8 + i] = f2bf(v);
    }
  }
}

// ---------------- mainK: fused gather + tail, 1024 thr, 1 block/CU ----------
// grid 768; block owns 128 rows. Gather: 16 waves x 8 rows. Tail: 8 waves x 16.
__global__ __launch_bounds__(1024, 1) void mainK(
    const float* __restrict__ x,
    const uint16_t* __restrict__ tcatp,
    const uint16_t* __restrict__ a1p,
    const uint16_t* __restrict__ wl2p,
    const uint16_t* __restrict__ woutp,
    const float* __restrict__ bf1p,
    const float* __restrict__ boutp,
    float* __restrict__ out)
{
  __shared__ __align__(16) unsigned char smem[162816];
  uint4* tbl4 = reinterpret_cast<uint4*>(smem);
  const char* tbl = reinterpret_cast<const char*>(smem);
  uint16_t* hst = reinterpret_cast<uint16_t*>(smem + 128000);   // 128 x 136 u16

  const int tid = threadIdx.x, lane = tid & 63, w = tid >> 6;   // w in 0..15
  const int r8 = lane >> 3, s = lane & 7;
  const int bid = blockIdx.x;

  // ---- compute this wave-row's 20 LDS byte-offsets ONCE (same both halves) ----
  const int myrow = w*8 + r8;
  uint32_t off[20];
  {
    const float* xr = x + ((size_t)bid*128 + myrow)*40;
    const f32x4 c0 = *reinterpret_cast<const f32x4*>(xr);
    const f32x4 c1 = *reinterpret_cast<const f32x4*>(xr + 4);
    const f32x4 c2 = *reinterpret_cast<const f32x4*>(xr + 8);
    const f32x4 c3 = *reinterpret_cast<const f32x4*>(xr + 12);
    const f32x4 c4 = *reinterpret_cast<const f32x4*>(xr + 16);
    const uint32_t sb = (uint32_t)s*16u;
    #pragma unroll
    for (int k = 0; k < 4; k++) {
      off[k]      = ((uint32_t)(k)*50u      + (uint32_t)c0[k])*128u + sb;
      off[4 + k]  = ((uint32_t)(4 + k)*50u  + (uint32_t)c1[k])*128u + sb;
      off[8 + k]  = ((uint32_t)(8 + k)*50u  + (uint32_t)c2[k])*128u + sb;
      off[12 + k] = ((uint32_t)(12 + k)*50u + (uint32_t)c3[k])*128u + sb;
      off[16 + k] = ((uint32_t)(16 + k)*50u + (uint32_t)c4[k])*128u + sb;
    }
  }

  // ====== phases A/B: LDS gather of each column half ======
  for (int h = 0; h < 2; h++) {
    const uint4* src = reinterpret_cast<const uint4*>(tcatp) + h*8000;
    for (int i = tid; i < 8000; i += 1024)
      GLDS16(src + i, tbl4 + i);
    __syncthreads();

    uint4 b[20];
    #pragma unroll
    for (int f = 0; f < 20; f++)
      b[f] = *reinterpret_cast<const uint4*>(tbl + off[f]);
    f32x2 p0 = {0.f,0.f}, p1 = {0.f,0.f}, p2 = {0.f,0.f}, p3 = {0.f,0.f};
    #pragma unroll
    for (int f = 0; f < 20; f++) {
      p0 += (f32x2){ bflo(b[f].x), bfhi(b[f].x) };
      p1 += (f32x2){ bflo(b[f].y), bfhi(b[f].y) };
      p2 += (f32x2){ bflo(b[f].z), bfhi(b[f].z) };
      p3 += (f32x2){ bflo(b[f].w), bfhi(b[f].w) };
    }
    const uint4 o = { cvtpk(p0[0], p0[1]), cvtpk(p1[0], p1[1]),
                      cvtpk(p2[0], p2[1]), cvtpk(p3[0], p3[1]) };
    *reinterpret_cast<uint4*>(hst + myrow*136 + 64*h + 8*s) = o;
    __syncthreads();
  }

  // ====== phase C: stage weights into dead table region ======
  uint16_t* wl2l = reinterpret_cast<uint16_t*>(smem);            // 32768 B
  uint16_t* wol  = reinterpret_cast<uint16_t*>(smem + 32768);    // 32768 B
  uint16_t* a1l  = reinterpret_cast<uint16_t*>(smem + 65536);    //  8192 B
  float*    bf1l = reinterpret_cast<float*>(smem + 73728);       //   512 B
  float*    boll = reinterpret_cast<float*>(smem + 74240);       //   512 B
  {
    for (int i = tid; i < 2048; i += 1024)
      GLDS16(reinterpret_cast<const uint4*>(wl2p) + i, reinterpret_cast<uint4*>(wl2l) + i);
    for (int i = tid; i < 2048; i += 1024)
      GLDS16(reinterpret_cast<const uint4*>(woutp) + i, reinterpret_cast<uint4*>(wol) + i);
    if (tid < 512)
      GLDS16(reinterpret_cast<const uint4*>(a1p) + tid, reinterpret_cast<uint4*>(a1l) + tid);
    else if (tid < 576)   // ONE full wave: bf1p|boutp contiguous in ws, bf1l|boll in LDS
      GLDS16(reinterpret_cast<const uint4*>(bf1p) + (tid - 512),
             reinterpret_cast<uint4*>(bf1l) + (tid - 512));
  }
  __syncthreads();

  // ====== tail: waves 0..7, 16 rows each (r11/r15 verified body) ======
  if (w < 8) {
    uint16_t* hb = reinterpret_cast<uint16_t*>(smem + 74752) + w*2176;  // 16x136 u16
    const int g = lane >> 4, c16 = lane & 15;
    const int row = w*16 + c16;
    const size_t grow = (size_t)bid*128 + row;

    // numeric bf16 fragment from x (lane-local; rows k>20 hit zero a1p rows)
    short8 xf;
    {
      uint32_t* xw = (uint32_t*)&xf;
      const float* xn = x + grow*40 + 20;
      if (g < 2) {
        const f32x4 a = *reinterpret_cast<const f32x4*>(xn + 8*g);
        const f32x4 b = *reinterpret_cast<const f32x4*>(xn + 8*g + 4);
        xw[0] = cvtpk(a[0], a[1]); xw[1] = cvtpk(a[2], a[3]);
        xw[2] = cvtpk(b[0], b[1]); xw[3] = cvtpk(b[2], b[3]);
      } else if (g == 2) {
        const f32x4 a = *reinterpret_cast<const f32x4*>(xn + 16);
        xw[0] = cvtpk(a[0], a[1]); xw[1] = cvtpk(a[2], a[3]);
        xw[2] = cvtpk(1.0f, 0.0f); xw[3] = 0;
      } else {
        xw[0] = 0; xw[1] = 0; xw[2] = 0; xw[3] = 0;
      }
    }

    // numeric fold: acc[t=2ks+hl][r] = cols 32ks+8g+4hl+r
    f32x4 acc[8];
    #pragma unroll
    for (int t = 0; t < 8; t++) {
      const short8 af = *reinterpret_cast<const short8*>(a1l + (t*64 + lane)*8);
      acc[t] = __builtin_amdgcn_mfma_f32_16x16x32_bf16(af, xf, (f32x4){0.f,0.f,0.f,0.f}, 0, 0, 0);
    }

    // add gathered categorical part from hstate (slot-major bf16)
    const uint16_t* h1row = hst + row*136;
    #pragma unroll
    for (int ks = 0; ks < 4; ks++)
      #pragma unroll
      for (int hl = 0; hl < 2; hl++) {
        const int inner = 8*g + 4*hl;
        const int tc = 2*ks + (inner >> 4);
        const int gc = (inner & 15) >> 2;
        const int jj = tc & 3;
        const int P = 64*(tc >> 2) + 8*(2*gc + (jj >> 1)) + 4*(jj & 1);
        const uint2 u = *reinterpret_cast<const uint2*>(h1row + P);
        const int t = 2*ks + hl;
        acc[t][0] += bflo(u.x); acc[t][1] += bfhi(u.x);
        acc[t][2] += bflo(u.y); acc[t][3] += bfhi(u.y);
      }

    // LN0 (gamma/beta folded downstream)
    float sA = 0.f, qA = 0.f;
    #pragma unroll
    for (int t = 0; t < 8; t++)
      #pragma unroll
      for (int r = 0; r < 4; r++) { const float v = acc[t][r]; sA += v; qA = fmaf(v, v, qA); }
    sA += __shfl_xor(sA, 16); sA += __shfl_xor(sA, 32);
    qA += __shfl_xor(qA, 16); qA += __shfl_xor(qA, 32);
    const float mu = sA * (1.f/128.f);
    const float rs = rsqrtf(qA*(1.f/128.f) - mu*mu + LN_EPS);

    short8 a2[4];
    #pragma unroll
    for (int ks = 0; ks < 4; ks++) {
      uint32_t* aw = (uint32_t*)&a2[ks];
      aw[0] = cvtpk((acc[2*ks][0]-mu)*rs,   (acc[2*ks][1]-mu)*rs);
      aw[1] = cvtpk((acc[2*ks][2]-mu)*rs,   (acc[2*ks][3]-mu)*rs);
      aw[2] = cvtpk((acc[2*ks+1][0]-mu)*rs, (acc[2*ks+1][1]-mu)*rs);
      aw[3] = cvtpk((acc[2*ks+1][2]-mu)*rs, (acc[2*ks+1][3]-mu)*rs);
    }

    // GEMM2': acc2 = z1 @ WL1' (+bf1')
    f32x4 acc2[8];
    __builtin_amdgcn_s_setprio(1);
    #pragma unroll
    for (int t = 0; t < 8; t++) {
      acc2[t] = *reinterpret_cast<const f32x4*>(bf1l + g*32 + t*4);
      #pragma unroll
      for (int ks = 0; ks < 4; ks++) {
        const short8 wf = *reinterpret_cast<const short8*>(wl2l + ((t*4 + ks)*64 + lane)*8);
        acc2[t] = __builtin_amdgcn_mfma_f32_16x16x32_bf16(wf, a2[ks], acc2[t], 0, 0, 0);
      }
    }
    __builtin_amdgcn_s_setprio(0);

    // LN1
    float s2 = 0.f, q2 = 0.f;
    #pragma unroll
    for (int t = 0; t < 8; t++)
      #pragma unroll
      for (int r = 0; r < 4; r++) { const float v = acc2[t][r]; s2 += v; q2 = fmaf(v, v, q2); }
    s2 += __shfl_xor(s2, 16); s2 += __shfl_xor(s2, 32);
    q2 += __shfl_xor(q2, 16); q2 += __shfl_xor(q2, 32);
    const float mu2 = s2 * (1.f/128.f);
    const float rs2 = rsqrtf(q2*(1.f/128.f) - mu2*mu2 + LN_EPS);

    #pragma unroll
    for (int t = 0; t < 8; t++) {
      const uint32x2 v = { cvtpk((acc2[t][0]-mu2)*rs2, (acc2[t][1]-mu2)*rs2),
                           cvtpk((acc2[t][2]-mu2)*rs2, (acc2[t][3]-mu2)*rs2) };
      *reinterpret_cast<uint32x2*>(hb + c16*136 + 16*t + 4*g) = v;
    }
    asm volatile("s_waitcnt lgkmcnt(0)" ::: "memory");

    // GEMM3': out = z2 @ Wout' + bout'
    short8 a3[4];
    #pragma unroll
    for (int ks = 0; ks < 4; ks++)
      a3[ks] = *reinterpret_cast<const short8*>(hb + c16*136 + 32*ks + 8*g);
    float* orow = out + grow*128;
    __builtin_amdgcn_s_setprio(1);
    #pragma unroll
    for (int t = 0; t < 8; t++) {
      f32x4 a3c = *reinterpret_cast<const f32x4*>(boll + g*32 + t*4);
      #pragma unroll
      for (int ks = 0; ks < 4; ks++) {
        const short8 wf = *reinterpret_cast<const short8*>(wol + ((t*4 + ks)*64 + lane)*8);
        a3c = __builtin_amdgcn_mfma_f32_16x16x32_bf16(wf, a3[ks], a3c, 0, 0, 0);
      }
      __builtin_nontemporal_store(a3c, reinterpret_cast<f32x4*>(orow + 16*t + 4*g));
    }
    __builtin_amdgcn_s_setprio(0);
  }
}

// ---------------- launcher ----------------
extern "C" void kernel_launch(void* const* d_in, const int* in_sizes, int n_in,
                              void* d_out, int out_size, void* d_ws, size_t ws_size,
                              hipStream_t stream)
{
  const float* x     = (const float*)d_in[0];
  const float* emb   = (const float*)d_in[1];
  const float* W_num = (const float*)d_in[2];
  const float* b_num = (const float*)d_in[3];
  const float* W_in  = (const float*)d_in[4];
  const float* b_in  = (const float*)d_in[5];
  const float* W1    = (const float*)d_in[6];
  const float* b1    = (const float*)d_in[7];
  const float* W2    = (const float*)d_in[8];
  const float* b2    = (const float*)d_in[9];
  const float* ln_g  = (const float*)d_in[10];
  const float* ln_b  = (const float*)d_in[11];
  const float* W_out = (const float*)d_in[12];
  const float* b_out = (const float*)d_in[13];
  float* out = (float*)d_out;

  char* ws = (char*)d_ws;
  float*    WLf   = (float*)(ws + 0);          // 131072 B
  float*    Bnum  = (float*)(ws + 131072);     //  10752 B
  float*    bfold = (float*)(ws + 141824);     //   1024 B
  uint16_t* tcatp = (uint16_t*)(ws + 142848);  // 256000 B
  uint16_t* wl2p  = (uint16_t*)(ws + 398848);  //  32768 B
  uint16_t* woutp = (uint16_t*)(ws + 431616);  //  32768 B
  uint16_t* a1p   = (uint16_t*)(ws + 464384);  //   8192 B
  float*    bf1p  = (float*)(ws + 472576);     //    512 B
  float*    boutp = (float*)(ws + 473088);     //    512 B

  pre1<<<dim3(312), dim3(128), 0, stream>>>(W_num, b_num, W_in, b_in, W1, b1, W2, b2,
                                            W_out, b_out, ln_g, ln_b,
                                            WLf, Bnum, bfold, woutp, boutp);
  pre2<<<dim3(1041), dim3(128), 0, stream>>>(emb, W_in, ln_g, ln_b, WLf, Bnum, bfold,
                                             tcatp, wl2p, bf1p, a1p);
  mainK<<<dim3(768), dim3(1024), 0, stream>>>(x, tcatp, a1p, wl2p, woutp,
                                              bf1p, boutp, out);
}

// Round 18
// 67.020 us; speedup vs baseline: 1.0502x; 1.0502x over previous
//
#include <hip/hip_runtime.h>
#include <hip/hip_bf16.h>
#include <stdint.h>
#include <stddef.h>

// ---------------------------------------------------------------------------
// FixedEmbedderNN — round 18: r15 verbatim (session-best measured: 67.7 us,
// absmax 0.03125). r17's two deltas (setprio, bias-merge) measured neutral
// and are removed. Structure:
//  pre1: WLf=W1@W2, Bnum, bfold, woutp (diag(g1)@W_out A-pack), boutp.
//  pre2: tcatp [2][20][50][64] bf16 slot-major; wl2p (diag(g0)@WL_1 A-pack);
//        bf1p; a1p (A1^T, 8-run col map).
//  mainK: 768 blocks x 1024 thr (1 block/CU). Phases: half-table GLDS stage ->
//   bank-perfect lane=(r8,s) gather (offsets precomputed once) -> hstate;
//   x2 halves; weight GLDS stage into dead table region; tail waves 0..7:
//   numeric MFMA + hstate add + LN0 + GEMM2' + LN1 + GEMM3' -> out.
// ---------------------------------------------------------------------------

typedef __attribute__((ext_vector_type(8))) short short8;
typedef __attribute__((ext_vector_type(4))) float f32x4;
typedef __attribute__((ext_vector_type(2))) float f32x2;
typedef __attribute__((ext_vector_type(2))) uint32_t uint32x2;

#define LN_EPS 1e-5f

#define GLDS16(g, l) __builtin_amdgcn_global_load_lds( \
    (const __attribute__((address_space(1))) uint32_t*)(g), \
    (__attribute__((address_space(3))) uint32_t*)(l), 16, 0, 0)

__device__ __forceinline__ float bflo(uint32_t u){ union{uint32_t u;float f;} c; c.u = u<<16; return c.f; }
__device__ __forceinline__ float bfhi(uint32_t u){ union{uint32_t u;float f;} c; c.u = u&0xffff0000u; return c.f; }
__device__ __forceinline__ uint16_t f2bf(float f){
  union{ __hip_bfloat16 h; uint16_t u; } c; c.h = __float2bfloat16(f); return c.u;
}
__device__ __forceinline__ uint32_t cvtpk(float lo, float hi){
  uint32_t r; asm("v_cvt_pk_bf16_f32 %0, %1, %2" : "=v"(r) : "v"(lo), "v"(hi)); return r;
}

// ---------------- precompute kernel 1 (no deps) ----------------
__global__ __launch_bounds__(128) void pre1(
    const float* __restrict__ W_num, const float* __restrict__ b_num,
    const float* __restrict__ W_in,  const float* __restrict__ b_in,
    const float* __restrict__ W1,    const float* __restrict__ b1,
    const float* __restrict__ W2,    const float* __restrict__ b2,
    const float* __restrict__ W_out, const float* __restrict__ b_out,
    const float* __restrict__ ln_g,  const float* __restrict__ ln_b,
    float* __restrict__ WLf,    // [2][128][128]
    float* __restrict__ Bnum,   // [21][128]
    float* __restrict__ bfold,  // [2][128]
    uint16_t* __restrict__ woutp, // Wout' transposed pack
    float* __restrict__ boutp)    // bout' permuted [g*32+t*4+r]
{
  const int b = blockIdx.x, j = threadIdx.x;
  if (b < 256) {                       // WL = W1@W2 per layer (4-way ILP)
    const int l = b >> 7, k = b & 127;
    const float* w1r = W1 + (l*128 + k)*256;
    const float* w2  = W2 + l*256*128;
    float sa = 0.f, sb = 0.f, sc = 0.f, sd = 0.f;
    for (int m = 0; m < 256; m += 4) {
      sa = fmaf(w1r[m],   w2[m*128 + j],       sa);
      sb = fmaf(w1r[m+1], w2[(m+1)*128 + j],   sb);
      sc = fmaf(w1r[m+2], w2[(m+2)*128 + j],   sc);
      sd = fmaf(w1r[m+3], w2[(m+3)*128 + j],   sd);
    }
    WLf[(l*128 + k)*128 + j] = (sa + sb) + (sc + sd);
  } else if (b < 277) {                // Bnum rows
    const int r = b - 256;
    if (r < 20) {
      const float* wn = W_num + r*32;
      const float* wi = W_in + (size_t)(20 + r)*32*128;
      float s = 0.f;
      for (int e = 0; e < 32; e++) s = fmaf(wn[e], wi[e*128 + j], s);
      Bnum[r*128 + j] = s;
    } else {
      float s = b_in[j];
      for (int f = 0; f < 20; f++) {
        const float* bn = b_num + f*32;
        const float* wi = W_in + (size_t)(20 + f)*32*128;
        for (int e = 0; e < 32; e++) s = fmaf(bn[e], wi[e*128 + j], s);
      }
      Bnum[20*128 + j] = s;
    }
  } else if (b < 279) {                // bfold = b1@W2 + b2
    const int l = b - 277;
    const float* b1r = b1 + l*256;
    const float* w2  = W2 + l*256*128;
    float s = b2[l*128 + j];
    for (int k = 0; k < 256; k++) s = fmaf(b1r[k], w2[k*128 + j], s);
    bfold[l*128 + j] = s;
  } else if (b < 311) {                // woutp: Wout' = diag(g1)@W_out, transposed A-pack
    const int p = b - 279, t = p >> 2, ks = p & 3;
    const int lane = j & 63, rep = j >> 6;
    const int col = 16*t + (lane & 15);
    for (int ii = 0; ii < 4; ii++) {
      const int i = rep*4 + ii;
      const int k = 32*ks + 8*(lane >> 4) + i;
      woutp[((t*4 + ks)*64 + lane)*8 + i] = f2bf(ln_g[128 + k] * W_out[k*128 + col]);
    }
  } else {                             // boutp (permuted): b1n@W_out + b_out
    const int t = (j >> 2) & 7, g = j >> 5, r = j & 3;
    const int col = 16*t + 4*g + r;
    float s = b_out[col];
    for (int k = 0; k < 128; k++) s = fmaf(ln_b[128 + k], W_out[k*128 + col], s);
    boutp[j] = s;
  }
}

// ---------------- precompute kernel 2 (depends on pre1) ----------------
__global__ __launch_bounds__(128) void pre2(
    const float* __restrict__ emb, const float* __restrict__ W_in,
    const float* __restrict__ ln_g, const float* __restrict__ ln_b,
    const float* __restrict__ WLf, const float* __restrict__ Bnum,
    const float* __restrict__ bfold,
    uint16_t* __restrict__ tcatp, // [2][20][50][64] bf16 slot-major
    uint16_t* __restrict__ wl2p,  // WL1' transposed pack
    float* __restrict__ bf1p,     // bf1' permuted
    uint16_t* __restrict__ a1p)   // A1^T pack, 8-run col map
{
  const int b = blockIdx.x, j = threadIdx.x;
  __shared__ float sh[128];
  if (b < 1000) {                      // Tcat1 = emb@W_in_slice@WL_0, slot-major store
    const int f = b / 50, c = b % 50;
    const float* e  = emb + (f*50 + c)*32;
    const float* wi = W_in + (size_t)f*32*128;
    float s = 0.f;
    for (int k = 0; k < 32; k++) s = fmaf(e[k], wi[k*128 + j], s);
    sh[j] = s;
    __syncthreads();
    float sa = 0.f, sb = 0.f, sc = 0.f, sd = 0.f;    // 4-way ILP
    for (int k = 0; k < 128; k += 4) {
      sa = fmaf(sh[k],   WLf[k*128 + j],       sa);
      sb = fmaf(sh[k+1], WLf[(k+1)*128 + j],   sb);
      sc = fmaf(sh[k+2], WLf[(k+2)*128 + j],   sc);
      sd = fmaf(sh[k+3], WLf[(k+3)*128 + j],   sd);
    }
    const float s2 = (sa + sb) + (sc + sd);
    const int t = j >> 4, g = (j >> 2) & 3, r = j & 3;
    const int h = t >> 2, jj = t & 3;
    const int slot = 2*g + (jj >> 1);
    tcatp[((h*20 + f)*50 + c)*64 + slot*8 + (jj & 1)*4 + r] = f2bf(s2);
  } else if (b < 1032) {               // wl2p: WL1' = diag(g0)@WL_1, transposed A-pack
    const int p = b - 1000, t = p >> 2, ks = p & 3;
    const int lane = j & 63, rep = j >> 6;
    const int col = 16*t + (lane & 15);
    const float* wl1 = WLf + 16384;
    for (int ii = 0; ii < 4; ii++) {
      const int i = rep*4 + ii;
      const int k = 32*ks + 8*(lane >> 4) + i;
      wl2p[((t*4 + ks)*64 + lane)*8 + i] = f2bf(ln_g[k] * wl1[k*128 + col]);
    }
  } else if (b == 1032) {              // bf1p (permuted): b0@WL_1 + bfold_1
    const int t = (j >> 2) & 7, g = j >> 5, r = j & 3;
    const int col = 16*t + 4*g + r;
    const float* wl1 = WLf + 16384;
    float s = bfold[128 + col];
    for (int k = 0; k < 128; k++) s = fmaf(ln_b[k], wl1[k*128 + col], s);
    bf1p[j] = s;
  } else {                             // a1p with 8-run col map (4-way ILP)
    const int t = b - 1033;
    const int lane = j & 63, rep = j >> 6;
    const int p = lane & 15;
    const int col = 32*(t >> 1) + 8*(p >> 2) + 4*(t & 1) + (p & 3);
    for (int ii = 0; ii < 4; ii++) {
      const int i = rep*4 + ii;
      const int k = 8*(lane >> 4) + i;
      float v = 0.f;
      if (k <= 20) {
        if (k == 20) v = bfold[col];
        float va = 0.f, vb = 0.f, vc = 0.f, vd = 0.f;
        for (int m = 0; m < 128; m += 4) {
          va = fmaf(Bnum[k*128 + m],   WLf[m*128 + col],       va);
          vb = fmaf(Bnum[k*128 + m+1], WLf[(m+1)*128 + col],   vb);
          vc = fmaf(Bnum[k*128 + m+2], WLf[(m+2)*128 + col],   vc);
          vd = fmaf(Bnum[k*128 + m+3], WLf[(m+3)*128 + col],   vd);
        }
        v += (va + vb) + (vc + vd);
      }
      a1p[(t*64 + lane)*8 + i] = f2bf(v);
    }
  }
}

// ---------------- mainK: fused gather + tail, 1024 thr, 1 block/CU ----------
// grid 768; block owns 128 rows. Gather: 16 waves x 8 rows. Tail: 8 waves x 16.
__global__ __launch_bounds__(1024, 1) void mainK(
    const float* __restrict__ x,
    const uint16_t* __restrict__ tcatp,
    const uint16_t* __restrict__ a1p,
    const uint16_t* __restrict__ wl2p,
    const uint16_t* __restrict__ woutp,
    const float* __restrict__ bf1p,
    const float* __restrict__ boutp,
    float* __restrict__ out)
{
  __shared__ __align__(16) unsigned char smem[162816];
  uint4* tbl4 = reinterpret_cast<uint4*>(smem);
  const char* tbl = reinterpret_cast<const char*>(smem);
  uint16_t* hst = reinterpret_cast<uint16_t*>(smem + 128000);   // 128 x 136 u16

  const int tid = threadIdx.x, lane = tid & 63, w = tid >> 6;   // w in 0..15
  const int r8 = lane >> 3, s = lane & 7;
  const int bid = blockIdx.x;

  // ---- compute this wave-row's 20 LDS byte-offsets ONCE (same both halves) ----
  const int myrow = w*8 + r8;
  uint32_t off[20];
  {
    const float* xr = x + ((size_t)bid*128 + myrow)*40;
    const f32x4 c0 = *reinterpret_cast<const f32x4*>(xr);
    const f32x4 c1 = *reinterpret_cast<const f32x4*>(xr + 4);
    const f32x4 c2 = *reinterpret_cast<const f32x4*>(xr + 8);
    const f32x4 c3 = *reinterpret_cast<const f32x4*>(xr + 12);
    const f32x4 c4 = *reinterpret_cast<const f32x4*>(xr + 16);
    const uint32_t sb = (uint32_t)s*16u;
    #pragma unroll
    for (int k = 0; k < 4; k++) {
      off[k]      = ((uint32_t)(k)*50u      + (uint32_t)c0[k])*128u + sb;
      off[4 + k]  = ((uint32_t)(4 + k)*50u  + (uint32_t)c1[k])*128u + sb;
      off[8 + k]  = ((uint32_t)(8 + k)*50u  + (uint32_t)c2[k])*128u + sb;
      off[12 + k] = ((uint32_t)(12 + k)*50u + (uint32_t)c3[k])*128u + sb;
      off[16 + k] = ((uint32_t)(16 + k)*50u + (uint32_t)c4[k])*128u + sb;
    }
  }

  // ====== phases A/B: LDS gather of each column half ======
  for (int h = 0; h < 2; h++) {
    const uint4* src = reinterpret_cast<const uint4*>(tcatp) + h*8000;
    for (int i = tid; i < 8000; i += 1024)
      GLDS16(src + i, tbl4 + i);
    __syncthreads();

    uint4 b[20];
    #pragma unroll
    for (int f = 0; f < 20; f++)
      b[f] = *reinterpret_cast<const uint4*>(tbl + off[f]);
    f32x2 p0 = {0.f,0.f}, p1 = {0.f,0.f}, p2 = {0.f,0.f}, p3 = {0.f,0.f};
    #pragma unroll
    for (int f = 0; f < 20; f++) {
      p0 += (f32x2){ bflo(b[f].x), bfhi(b[f].x) };
      p1 += (f32x2){ bflo(b[f].y), bfhi(b[f].y) };
      p2 += (f32x2){ bflo(b[f].z), bfhi(b[f].z) };
      p3 += (f32x2){ bflo(b[f].w), bfhi(b[f].w) };
    }
    const uint4 o = { cvtpk(p0[0], p0[1]), cvtpk(p1[0], p1[1]),
                      cvtpk(p2[0], p2[1]), cvtpk(p3[0], p3[1]) };
    *reinterpret_cast<uint4*>(hst + myrow*136 + 64*h + 8*s) = o;
    __syncthreads();
  }

  // ====== phase C: stage weights into dead table region ======
  uint16_t* wl2l = reinterpret_cast<uint16_t*>(smem);            // 32768 B
  uint16_t* wol  = reinterpret_cast<uint16_t*>(smem + 32768);    // 32768 B
  uint16_t* a1l  = reinterpret_cast<uint16_t*>(smem + 65536);    //  8192 B
  float*    bf1l = reinterpret_cast<float*>(smem + 73728);       //   512 B
  float*    boll = reinterpret_cast<float*>(smem + 74240);       //   512 B
  {
    for (int i = tid; i < 2048; i += 1024)
      GLDS16(reinterpret_cast<const uint4*>(wl2p) + i, reinterpret_cast<uint4*>(wl2l) + i);
    for (int i = tid; i < 2048; i += 1024)
      GLDS16(reinterpret_cast<const uint4*>(woutp) + i, reinterpret_cast<uint4*>(wol) + i);
    if (tid < 512)
      GLDS16(reinterpret_cast<const uint4*>(a1p) + tid, reinterpret_cast<uint4*>(a1l) + tid);
    else if (tid < 544)
      GLDS16(reinterpret_cast<const uint4*>(bf1p) + (tid - 512), reinterpret_cast<uint4*>(bf1l) + (tid - 512));
    else if (tid < 576)
      GLDS16(reinterpret_cast<const uint4*>(boutp) + (tid - 544), reinterpret_cast<uint4*>(boll) + (tid - 544));
  }
  __syncthreads();

  // ====== tail: waves 0..7, 16 rows each ======
  if (w < 8) {
    uint16_t* hb = reinterpret_cast<uint16_t*>(smem + 74752) + w*2176;  // 16x136 u16
    const int g = lane >> 4, c16 = lane & 15;
    const int row = w*16 + c16;
    const size_t grow = (size_t)bid*128 + row;

    // numeric bf16 fragment from x (lane-local; rows k>20 hit zero a1p rows)
    short8 xf;
    {
      uint32_t* xw = (uint32_t*)&xf;
      const float* xn = x + grow*40 + 20;
      if (g < 2) {
        const f32x4 a = *reinterpret_cast<const f32x4*>(xn + 8*g);
        const f32x4 b = *reinterpret_cast<const f32x4*>(xn + 8*g + 4);
        xw[0] = cvtpk(a[0], a[1]); xw[1] = cvtpk(a[2], a[3]);
        xw[2] = cvtpk(b[0], b[1]); xw[3] = cvtpk(b[2], b[3]);
      } else if (g == 2) {
        const f32x4 a = *reinterpret_cast<const f32x4*>(xn + 16);
        xw[0] = cvtpk(a[0], a[1]); xw[1] = cvtpk(a[2], a[3]);
        xw[2] = cvtpk(1.0f, 0.0f); xw[3] = 0;
      } else {
        xw[0] = 0; xw[1] = 0; xw[2] = 0; xw[3] = 0;
      }
    }

    // numeric fold: acc[t=2ks+hl][r] = cols 32ks+8g+4hl+r
    f32x4 acc[8];
    #pragma unroll
    for (int t = 0; t < 8; t++) {
      const short8 af = *reinterpret_cast<const short8*>(a1l + (t*64 + lane)*8);
      acc[t] = __builtin_amdgcn_mfma_f32_16x16x32_bf16(af, xf, (f32x4){0.f,0.f,0.f,0.f}, 0, 0, 0);
    }

    // add gathered categorical part from hstate (slot-major bf16)
    const uint16_t* h1row = hst + row*136;
    #pragma unroll
    for (int ks = 0; ks < 4; ks++)
      #pragma unroll
      for (int hl = 0; hl < 2; hl++) {
        const int inner = 8*g + 4*hl;
        const int tc = 2*ks + (inner >> 4);
        const int gc = (inner & 15) >> 2;
        const int jj = tc & 3;
        const int P = 64*(tc >> 2) + 8*(2*gc + (jj >> 1)) + 4*(jj & 1);
        const uint2 u = *reinterpret_cast<const uint2*>(h1row + P);
        const int t = 2*ks + hl;
        acc[t][0] += bflo(u.x); acc[t][1] += bfhi(u.x);
        acc[t][2] += bflo(u.y); acc[t][3] += bfhi(u.y);
      }

    // LN0 (gamma/beta folded downstream)
    float sA = 0.f, qA = 0.f;
    #pragma unroll
    for (int t = 0; t < 8; t++)
      #pragma unroll
      for (int r = 0; r < 4; r++) { const float v = acc[t][r]; sA += v; qA = fmaf(v, v, qA); }
    sA += __shfl_xor(sA, 16); sA += __shfl_xor(sA, 32);
    qA += __shfl_xor(qA, 16); qA += __shfl_xor(qA, 32);
    const float mu = sA * (1.f/128.f);
    const float rs = rsqrtf(qA*(1.f/128.f) - mu*mu + LN_EPS);

    short8 a2[4];
    #pragma unroll
    for (int ks = 0; ks < 4; ks++) {
      uint32_t* aw = (uint32_t*)&a2[ks];
      aw[0] = cvtpk((acc[2*ks][0]-mu)*rs,   (acc[2*ks][1]-mu)*rs);
      aw[1] = cvtpk((acc[2*ks][2]-mu)*rs,   (acc[2*ks][3]-mu)*rs);
      aw[2] = cvtpk((acc[2*ks+1][0]-mu)*rs, (acc[2*ks+1][1]-mu)*rs);
      aw[3] = cvtpk((acc[2*ks+1][2]-mu)*rs, (acc[2*ks+1][3]-mu)*rs);
    }

    // GEMM2': acc2 = z1 @ WL1' (+bf1')
    f32x4 acc2[8];
    #pragma unroll
    for (int t = 0; t < 8; t++) {
      acc2[t] = *reinterpret_cast<const f32x4*>(bf1l + g*32 + t*4);
      #pragma unroll
      for (int ks = 0; ks < 4; ks++) {
        const short8 wf = *reinterpret_cast<const short8*>(wl2l + ((t*4 + ks)*64 + lane)*8);
        acc2[t] = __builtin_amdgcn_mfma_f32_16x16x32_bf16(wf, a2[ks], acc2[t], 0, 0, 0);
      }
    }

    // LN1
    float s2 = 0.f, q2 = 0.f;
    #pragma unroll
    for (int t = 0; t < 8; t++)
      #pragma unroll
      for (int r = 0; r < 4; r++) { const float v = acc2[t][r]; s2 += v; q2 = fmaf(v, v, q2); }
    s2 += __shfl_xor(s2, 16); s2 += __shfl_xor(s2, 32);
    q2 += __shfl_xor(q2, 16); q2 += __shfl_xor(q2, 32);
    const float mu2 = s2 * (1.f/128.f);
    const float rs2 = rsqrtf(q2*(1.f/128.f) - mu2*mu2 + LN_EPS);

    #pragma unroll
    for (int t = 0; t < 8; t++) {
      const uint32x2 v = { cvtpk((acc2[t][0]-mu2)*rs2, (acc2[t][1]-mu2)*rs2),
                           cvtpk((acc2[t][2]-mu2)*rs2, (acc2[t][3]-mu2)*rs2) };
      *reinterpret_cast<uint32x2*>(hb + c16*136 + 16*t + 4*g) = v;
    }
    asm volatile("s_waitcnt lgkmcnt(0)" ::: "memory");

    // GEMM3': out = z2 @ Wout' + bout'
    short8 a3[4];
    #pragma unroll
    for (int ks = 0; ks < 4; ks++)
      a3[ks] = *reinterpret_cast<const short8*>(hb + c16*136 + 32*ks + 8*g);
    float* orow = out + grow*128;
    #pragma unroll
    for (int t = 0; t < 8; t++) {
      f32x4 a3c = *reinterpret_cast<const f32x4*>(boll + g*32 + t*4);
      #pragma unroll
      for (int ks = 0; ks < 4; ks++) {
        const short8 wf = *reinterpret_cast<const short8*>(wol + ((t*4 + ks)*64 + lane)*8);
        a3c = __builtin_amdgcn_mfma_f32_16x16x32_bf16(wf, a3[ks], a3c, 0, 0, 0);
      }
      __builtin_nontemporal_store(a3c, reinterpret_cast<f32x4*>(orow + 16*t + 4*g));
    }
  }
}

// ---------------- launcher ----------------
extern "C" void kernel_launch(void* const* d_in, const int* in_sizes, int n_in,
                              void* d_out, int out_size, void* d_ws, size_t ws_size,
                              hipStream_t stream)
{
  const float* x     = (const float*)d_in[0];
  const float* emb   = (const float*)d_in[1];
  const float* W_num = (const float*)d_in[2];
  const float* b_num = (const float*)d_in[3];
  const float* W_in  = (const float*)d_in[4];
  const float* b_in  = (const float*)d_in[5];
  const float* W1    = (const float*)d_in[6];
  const float* b1    = (const float*)d_in[7];
  const float* W2    = (const float*)d_in[8];
  const float* b2    = (const float*)d_in[9];
  const float* ln_g  = (const float*)d_in[10];
  const float* ln_b  = (const float*)d_in[11];
  const float* W_out = (const float*)d_in[12];
  const float* b_out = (const float*)d_in[13];
  float* out = (float*)d_out;

  char* ws = (char*)d_ws;
  float*    WLf   = (float*)(ws + 0);          // 131072 B
  float*    Bnum  = (float*)(ws + 131072);     //  10752 B
  float*    bfold = (float*)(ws + 141824);     //   1024 B
  uint16_t* tcatp = (uint16_t*)(ws + 142848);  // 256000 B
  uint16_t* wl2p  = (uint16_t*)(ws + 398848);  //  32768 B
  uint16_t* woutp = (uint16_t*)(ws + 431616);  //  32768 B
  uint16_t* a1p   = (uint16_t*)(ws + 464384);  //   8192 B
  float*    bf1p  = (float*)(ws + 472576);     //    512 B
  float*    boutp = (float*)(ws + 473088);     //    512 B

  pre1<<<dim3(312), dim3(128), 0, stream>>>(W_num, b_num, W_in, b_in, W1, b1, W2, b2,
                                            W_out, b_out, ln_g, ln_b,
                                            WLf, Bnum, bfold, woutp, boutp);
  pre2<<<dim3(1041), dim3(128), 0, stream>>>(emb, W_in, ln_g, ln_b, WLf, Bnum, bfold,
                                             tcatp, wl2p, bf1p, a1p);
  mainK<<<dim3(768), dim3(1024), 0, stream>>>(x, tcatp, a1p, wl2p, woutp,
                                              bf1p, boutp, out);
}